// Round 10
// baseline (2315.398 us; speedup 1.0000x reference)
//
#include <hip/hip_runtime.h>
#include <float.h>

#define BB   8
#define NN   4096
#define SS   2048
#define MID  32
#define COUT 64
#define CAT  67            // 3 + 64
#define M1   (BB*NN)       // 32768
#define M2   (BB*SS)       // 16384
#define EPSB 1e-5f
#define NCHUNK 64          // chunks per batch
#define CSZ    32          // centroids per chunk

// ---- control (int offsets; each hot word on its own 64B line) ----
#define I_B0   0
#define I_B1   16
#define I_B2   32
#define I_TKT  64
#define I_PROG 80          // + b*16
// ---- float offsets ----
#define WS_RED2  256                     // 128 floats BN2 sums (atomic)
#define WS_RED1  400                     // 64 x 9 moment partials
#define WS_FPS   1024                    // 16384 ints
#define WS_FEATS (1024 + 16384)          // 32768*64 floats
#define WS_POOL  (WS_FEATS + M1*COUT)    // 16384*67 floats

// ---- shared memory union (max = SC ~148 KB -> 1 block/CU) ----
struct SA  { float red[8][9]; };
struct SB4 { float4 Pc[NN]; alignas(16) unsigned long long sv[2][8]; };
struct SB3 { float W1s[96]; float abv[64]; float W2s[2048]; float b2s[64]; float mom[9]; };
struct SC  { float4 Pq[NN]; unsigned long long cand[CSZ][257]; int fin[CSZ][16];
             float W3s[64 * CAT]; float b3s[64]; float ps[128]; int tkt; };
struct SE  { float W3t[CAT * 64]; float W4s[4096]; float b3s[64]; float b4s[64]; float ab[128]; };
union  SU  { SA a; SB4 b4; SB3 b3; SC c; SE e; };

__device__ __forceinline__ unsigned long long u64max(unsigned long long a,
                                                     unsigned long long b) {
    return a > b ? a : b;
}

template <int CTRL>
__device__ __forceinline__ unsigned long long dpp_swap_max(unsigned long long v) {
    int lo = (int)(unsigned)v;
    int hi = (int)(unsigned)(v >> 32);
    int olo = __builtin_amdgcn_update_dpp(0, lo, CTRL, 0xF, 0xF, false);
    int ohi = __builtin_amdgcn_update_dpp(0, hi, CTRL, 0xF, 0xF, false);
    unsigned long long ov = ((unsigned long long)(unsigned)ohi << 32) | (unsigned)olo;
    return u64max(v, ov);   // keys >= 0, so lanes getting old=0 are no-ops
}

// sleepy single-use device barrier; long sleep to keep its line cold
__device__ __forceinline__ void barrier_join(int* ctr, int target) {
    __syncthreads();
    if (threadIdx.x == 0) {
        __threadfence();
        atomicAdd(ctr, 1);
        while (__hip_atomic_load(ctr, __ATOMIC_RELAXED, __HIP_MEMORY_SCOPE_AGENT) < target)
            __builtin_amdgcn_s_sleep(64);
        __threadfence();
    }
    __syncthreads();
}

// keep smallest-16 u64 keys; cmaxv/cpos track current max slot
__device__ __forceinline__ void top16_insert(unsigned long long* cv,
                                             unsigned long long newv,
                                             unsigned long long& cmaxv, int& cpos) {
#pragma unroll
    for (int j = 0; j < 16; j++) cv[j] = (j == cpos) ? newv : cv[j];
    unsigned long long m1a[8]; int p1a[8];
#pragma unroll
    for (int j = 0; j < 8; j++) {
        bool s = cv[2 * j + 1] > cv[2 * j];
        m1a[j] = s ? cv[2 * j + 1] : cv[2 * j];
        p1a[j] = s ? 2 * j + 1 : 2 * j;
    }
    unsigned long long m2a[4]; int p2a[4];
#pragma unroll
    for (int j = 0; j < 4; j++) {
        bool s = m1a[2 * j + 1] > m1a[2 * j];
        m2a[j] = s ? m1a[2 * j + 1] : m1a[2 * j];
        p2a[j] = s ? p1a[2 * j + 1] : p1a[2 * j];
    }
    unsigned long long m3a, m3b; int p3a, p3b;
    { bool s = m2a[1] > m2a[0]; m3a = s ? m2a[1] : m2a[0]; p3a = s ? p2a[1] : p2a[0]; }
    { bool s = m2a[3] > m2a[2]; m3b = s ? m2a[3] : m2a[2]; p3b = s ? p2a[3] : p2a[2]; }
    bool s = m3b > m3a;
    cmaxv = s ? m3b : m3a; cpos = s ? p3b : p3a;
}

__global__ __launch_bounds__(512) void fused(
        const float* __restrict__ xin,
        const float* __restrict__ W1, const float* __restrict__ b1,
        const float* __restrict__ g1, const float* __restrict__ be1,
        const float* __restrict__ W2, const float* __restrict__ b2,
        const float* __restrict__ W3, const float* __restrict__ b3,
        const float* __restrict__ g2, const float* __restrict__ be2,
        const float* __restrict__ W4, const float* __restrict__ b4,
        float* __restrict__ ws, float* __restrict__ out) {
    __shared__ SU sm;
    int blk = blockIdx.x, tid = threadIdx.x;
    int* ctri  = (int*)ws;
    int* fidxg = (int*)(ws + WS_FPS);
    (void)b1;

    if (blk < 8) {
        //======== FPS producer: DPP row_bcast reduce, named-reg publish ========
        int b = blk;
        const float* xb = xin + (size_t)b * NN * 3;
        int* fob = fidxg + b * SS;
        int* progb = ctri + I_PROG + b * 16;
        float px[8], py[8], pz[8], dist[8];
#pragma unroll
        for (int k = 0; k < 8; k++) {
            int i = tid + (k << 9);
            float x = xb[3 * i], y = xb[3 * i + 1], z = xb[3 * i + 2];
            px[k] = x; py[k] = y; pz[k] = z; dist[k] = FLT_MAX;
            sm.b4.Pc[i] = make_float4(x, y, z, 0.f);
        }
        __syncthreads();
        float4 c0 = sm.b4.Pc[0];
        float cx = c0.x, cy = c0.y, cz = c0.z;
        int wid = tid >> 6, lane = tid & 63;
        int r0 = 0, r1 = 0, r2 = 0, r3 = 0, r4 = 0, r5 = 0, r6 = 0, r7 = 0;
        for (int t = 1; t < SS; t++) {
            float bv = -1.f; int bi = 0;
#pragma unroll
            for (int k = 0; k < 8; k++) {
                float dx = px[k] - cx, dy = py[k] - cy, dz = pz[k] - cz;
                float d = fmaf(dz, dz, fmaf(dy, dy, dx * dx));
                float nd = fminf(dist[k], d);
                dist[k] = nd;
                bool bt = nd > bv;
                bv = bt ? nd : bv; bi = bt ? (tid + (k << 9)) : bi;
            }
            unsigned long long v =
                ((unsigned long long)__float_as_uint(bv) << 32) | (unsigned)(~bi);
            v = dpp_swap_max<0xB1>(v);     // quad xor1
            v = dpp_swap_max<0x4E>(v);     // quad xor2
            v = dpp_swap_max<0x141>(v);    // row_half_mirror
            v = dpp_swap_max<0x140>(v);    // row_mirror -> 16-lane row max
            v = dpp_swap_max<0x142>(v);    // row_bcast15: fold row pairs
            v = dpp_swap_max<0x143>(v);    // row_bcast31: lanes 32-63 = wave max
            int par = t & 1;
            if (lane == 63) sm.b4.sv[par][wid] = v;
            __syncthreads();
            const ulonglong2* sp = (const ulonglong2*)sm.b4.sv[par];
            ulonglong2 q0 = sp[0], q1 = sp[1], q2 = sp[2], q3 = sp[3];
            unsigned long long m0 = u64max(q0.x, q0.y), m1 = u64max(q1.x, q1.y);
            unsigned long long m2 = u64max(q2.x, q2.y), m3 = u64max(q3.x, q3.y);
            unsigned long long best = u64max(u64max(m0, m1), u64max(m2, m3));
            int bsel = (int)(~(unsigned)best);
            float4 cc = sm.b4.Pc[bsel];
            cx = cc.x; cy = cc.y; cz = cc.z;
            if (tid == 0) {
                switch (t & 7) {
                    case 0: r0 = bsel; break;
                    case 1: r1 = bsel; break;
                    case 2: r2 = bsel; break;
                    case 3: r3 = bsel; break;
                    case 4: r4 = bsel; break;
                    case 5: r5 = bsel; break;
                    case 6: r6 = bsel; break;
                    default: r7 = bsel; break;
                }
                if ((t & 7) == 7) {
                    *(int4*)(fob + t - 7) = make_int4(r0, r1, r2, r3);
                    *(int4*)(fob + t - 3) = make_int4(r4, r5, r6, r7);
                    if ((t & 31) == 31)
                        __hip_atomic_store(progb, t + 1, __ATOMIC_RELEASE,
                                           __HIP_MEMORY_SCOPE_AGENT);
                }
            }
        }
    } else {
        //======== Phase A: BN1 moments (blocks 8-71) ========
        if (blk < 72) {
            int p = (blk - 8) * 512 + tid;
            float x0 = xin[3 * p], x1 = xin[3 * p + 1], x2 = xin[3 * p + 2];
            float r[9];
            r[0] = x0; r[1] = x1; r[2] = x2;
            r[3] = x0 * x0; r[4] = x0 * x1; r[5] = x0 * x2;
            r[6] = x1 * x1; r[7] = x1 * x2; r[8] = x2 * x2;
#pragma unroll
            for (int m = 32; m; m >>= 1) {
#pragma unroll
                for (int q = 0; q < 9; q++) r[q] += __shfl_down(r[q], m, 64);
            }
            if ((tid & 63) == 0) {
#pragma unroll
                for (int q = 0; q < 9; q++) sm.a.red[tid >> 6][q] = r[q];
            }
            __syncthreads();
            if (tid == 0) {
#pragma unroll
                for (int q = 0; q < 9; q++) {
                    float s = 0.f;
#pragma unroll
                    for (int w = 0; w < 8; w++) s += sm.a.red[w][q];
                    ws[WS_RED1 + (blk - 8) * 9 + q] = s;
                }
            }
            barrier_join(ctri + I_B0, 64);
            //======== feats = conv2(relu(bn(conv1))) ========
            for (int j = tid; j < 96; j += 512) sm.b3.W1s[j] = W1[j];
            if (tid < 64) sm.b3.b2s[tid] = b2[tid];
            for (int j = tid; j < 2048; j += 512) sm.b3.W2s[j] = W2[j];
            if (tid < 9) {
                float s = 0.f;
                for (int k = 0; k < 64; k++) s += ws[WS_RED1 + k * 9 + tid];
                sm.b3.mom[tid] = s;
            }
            __syncthreads();
            if (tid < MID) {
                float S0 = sm.b3.mom[0], S1 = sm.b3.mom[1], S2 = sm.b3.mom[2];
                float C00 = sm.b3.mom[3], C01 = sm.b3.mom[4], C02 = sm.b3.mom[5];
                float C11 = sm.b3.mom[6], C12 = sm.b3.mom[7], C22 = sm.b3.mom[8];
                float w0 = W1[3 * tid], w1 = W1[3 * tid + 1], w2 = W1[3 * tid + 2];
                float invM = 1.f / (float)M1;
                float meanc = (w0 * S0 + w1 * S1 + w2 * S2) * invM;
                float wCw = w0 * w0 * C00 + w1 * w1 * C11 + w2 * w2 * C22 +
                            2.f * (w0 * w1 * C01 + w0 * w2 * C02 + w1 * w2 * C12);
                float var = wCw * invM - meanc * meanc;
                float a = g1[tid] * rsqrtf(var + EPSB);
                sm.b3.abv[tid] = a;
                sm.b3.abv[MID + tid] = be1[tid] - meanc * a;
            }
            __syncthreads();
            int p2 = (blk - 8) * 512 + tid;
            float y0 = xin[3 * p2], y1 = xin[3 * p2 + 1], y2 = xin[3 * p2 + 2];
            float h[MID];
#pragma unroll
            for (int o = 0; o < MID; o++) {
                float y = fmaf(sm.b3.W1s[3 * o + 2], y2,
                         fmaf(sm.b3.W1s[3 * o + 1], y1, sm.b3.W1s[3 * o] * y0));
                h[o] = fmaxf(0.f, fmaf(sm.b3.abv[o], y, sm.b3.abv[MID + o]));
            }
            float* fo = ws + WS_FEATS + (size_t)p2 * COUT;
#pragma unroll
            for (int j = 0; j < COUT; j += 4) {
                float a0 = sm.b3.b2s[j], a1v = sm.b3.b2s[j + 1];
                float a2v = sm.b3.b2s[j + 2], a3v = sm.b3.b2s[j + 3];
#pragma unroll
                for (int o = 0; o < MID; o++) {
                    float hv = h[o];
                    a0  = fmaf(sm.b3.W2s[(j)     * MID + o], hv, a0);
                    a1v = fmaf(sm.b3.W2s[(j + 1) * MID + o], hv, a1v);
                    a2v = fmaf(sm.b3.W2s[(j + 2) * MID + o], hv, a2v);
                    a3v = fmaf(sm.b3.W2s[(j + 3) * MID + o], hv, a3v);
                }
                *(float4*)(fo + j) = make_float4(a0, a1v, a2v, a3v);
            }
        }
        barrier_join(ctri + I_B1, 248);   // feats visible to all consumers

        //======== consumer: load W3 once, then ticket loop w/ fused BN2 ========
        for (int j = tid; j < 64 * CAT; j += 512) sm.c.W3s[j] = W3[j];
        if (tid < 64) sm.c.b3s[tid] = b3[tid];
        if (tid < 128) sm.c.ps[tid] = 0.f;
        __syncthreads();
        int c0ch = (tid & 15) * 4;                      // 4 BN2 channels per thread
        float bsum[4] = {0.f, 0.f, 0.f, 0.f}, bsq[4] = {0.f, 0.f, 0.f, 0.f};
        int curb = -1;
        for (;;) {
            if (tid == 0) sm.c.tkt = atomicAdd(ctri + I_TKT, 1);
            __syncthreads();
            int tk = sm.c.tkt;
            if (tk >= BB * NCHUNK) break;
            int b = tk & 7, c = tk >> 3;
            if (b != curb) {
                const float* xb = xin + (size_t)b * NN * 3;
                for (int j = tid; j < NN; j += 512) {
                    float x = xb[3 * j], y = xb[3 * j + 1], z = xb[3 * j + 2];
                    sm.c.Pq[j] = make_float4(x, y, z, (x * x + y * y) + z * z);
                }
                curb = b;
            }
            if (tid == 0) {               // wait for FPS prefix (cold polling)
                int* progb = ctri + I_PROG + b * 16;
                int need = (c + 1) * CSZ;
                while (__hip_atomic_load(progb, __ATOMIC_RELAXED,
                                         __HIP_MEMORY_SCOPE_AGENT) < need)
                    __builtin_amdgcn_s_sleep(64);
                (void)__hip_atomic_load(progb, __ATOMIC_ACQUIRE,
                                        __HIP_MEMORY_SCOPE_AGENT);
            }
            __syncthreads();
            int cc = tid >> 4, q = tid & 15;   // 32 centroids x 16 lanes
            int s = c * CSZ + cc;
            int sg = b * SS + s;
            int ci = fidxg[sg];
            float4 cen = sm.c.Pq[ci];
            float an = cen.w;
            unsigned long long cv[16];
#pragma unroll
            for (int j = 0; j < 16; j++) cv[j] = ~0ULL;
            unsigned long long cmaxv = ~0ULL; int cpos = 0;
            for (int n0 = 0; n0 < 256; n0++) {
                int n = (q << 8) + ((n0 + q) & 255);
                float4 qq = sm.c.Pq[n];
                float dot = fmaf(cen.z, qq.z, fmaf(cen.y, qq.y, cen.x * qq.x));
                float dd = (an + qq.w) - 2.f * dot;
                unsigned db = __float_as_uint(dd);
                db ^= (unsigned)(((int)db >> 31) | 0x80000000u);
                unsigned long long newv = ((unsigned long long)db << 32) | (unsigned)n;
                if (newv < cmaxv) top16_insert(cv, newv, cmaxv, cpos);
            }
#pragma unroll
            for (int j = 0; j < 16; j++)         // (j+q)&15: break 128B bank alias
                sm.c.cand[cc][q * 16 + ((j + q) & 15)] = cv[j];
            __syncthreads();
            if (tid < CSZ) {              // merge 256 -> 16 per centroid
                unsigned long long mv[16];
#pragma unroll
                for (int j = 0; j < 16; j++) mv[j] = ~0ULL;
                unsigned long long mx = ~0ULL; int mp = 0;
                for (int k = 0; k < 256; k++) {
                    unsigned long long e = sm.c.cand[tid][k];
                    if (e < mx) top16_insert(mv, e, mx, mp);
                }
#pragma unroll
                for (int j = 0; j < 16; j++) sm.c.fin[tid][j] = (int)(unsigned)mv[j];
            }
            __syncthreads();
            int idxs[16];
#pragma unroll
            for (int j = 0; j < 16; j++) idxs[j] = sm.c.fin[cc][j];
            const float* feats = ws + WS_FEATS + (size_t)b * NN * COUT;
            float4 acc = make_float4(-FLT_MAX, -FLT_MAX, -FLT_MAX, -FLT_MAX);
#pragma unroll 4
            for (int k = 0; k < 16; k++) {
                const float4* fp = (const float4*)(feats + (size_t)idxs[k] * COUT) + q;
                float4 v0 = fp[0];
                acc.x = fmaxf(acc.x, v0.x); acc.y = fmaxf(acc.y, v0.y);
                acc.z = fmaxf(acc.z, v0.z); acc.w = fmaxf(acc.w, v0.w);
            }
            float* po = ws + WS_POOL + (size_t)sg * CAT;
            po[3 + q * 4] = acc.x; po[4 + q * 4] = acc.y;
            po[5 + q * 4] = acc.z; po[6 + q * 4] = acc.w;
            if (q == 0) {
                float rx = -FLT_MAX, ry = -FLT_MAX, rz = -FLT_MAX;
#pragma unroll
                for (int k = 0; k < 16; k++) {
                    float4 p = sm.c.Pq[idxs[k]];
                    rx = fmaxf(rx, p.x - cen.x);
                    ry = fmaxf(ry, p.y - cen.y);
                    rz = fmaxf(rz, p.z - cen.z);
                }
                po[0] = rx; po[1] = ry; po[2] = rz;
            }
            __syncthreads();              // all 16 q-lanes wrote the row
            // fused BN2 partial: row (c*32 + tid>>4), channels c0ch..+3
            {
                int rrow = b * SS + c * CSZ + (tid >> 4);
                const float* rp = ws + WS_POOL + (size_t)rrow * CAT;
                float y0 = sm.c.b3s[c0ch],     y1 = sm.c.b3s[c0ch + 1];
                float y2 = sm.c.b3s[c0ch + 2], y3 = sm.c.b3s[c0ch + 3];
                for (int j = 0; j < CAT; j++) {
                    float pj = rp[j];
                    y0 = fmaf(sm.c.W3s[(c0ch)     * CAT + j], pj, y0);
                    y1 = fmaf(sm.c.W3s[(c0ch + 1) * CAT + j], pj, y1);
                    y2 = fmaf(sm.c.W3s[(c0ch + 2) * CAT + j], pj, y2);
                    y3 = fmaf(sm.c.W3s[(c0ch + 3) * CAT + j], pj, y3);
                }
                bsum[0] += y0; bsq[0] = fmaf(y0, y0, bsq[0]);
                bsum[1] += y1; bsq[1] = fmaf(y1, y1, bsq[1]);
                bsum[2] += y2; bsq[2] = fmaf(y2, y2, bsq[2]);
                bsum[3] += y3; bsq[3] = fmaf(y3, y3, bsq[3]);
            }
        }
        // flush BN2 partials: LDS reduce then 128 global atomics
#pragma unroll
        for (int u = 0; u < 4; u++) {
            atomicAdd(&sm.c.ps[c0ch + u], bsum[u]);
            atomicAdd(&sm.c.ps[64 + c0ch + u], bsq[u]);
        }
        __syncthreads();
        if (tid < 128) atomicAdd(ws + WS_RED2 + tid, sm.c.ps[tid]);
        __syncthreads();
    }

    //======== prefetch phase-D weights into registers (hidden under barrier) ========
    float wpre[17];
#pragma unroll
    for (int u = 0; u < 9; u++) {
        int lin = u * 512 + tid;
        wpre[u] = (lin < CAT * 64) ? W3[(lin & 63) * CAT + (lin >> 6)] : 0.f;
    }
#pragma unroll
    for (int u = 0; u < 8; u++) wpre[9 + u] = W4[u * 512 + tid];
    barrier_join(ctri + I_B2, 256);

    //======== D: final MLP (all 256 blocks, 64 rows each) ========
    {
#pragma unroll
        for (int u = 0; u < 9; u++) {
            int lin = u * 512 + tid;
            if (lin < CAT * 64) sm.e.W3t[lin] = wpre[u];
        }
#pragma unroll
        for (int u = 0; u < 8; u++) sm.e.W4s[u * 512 + tid] = wpre[9 + u];
        if (tid < 64) {
            sm.e.b3s[tid] = b3[tid]; sm.e.b4s[tid] = b4[tid];
            float inv = 1.f / (float)M2;
            float mean = ws[WS_RED2 + tid] * inv;
            float var = ws[WS_RED2 + 64 + tid] * inv - mean * mean;
            float a = g2[tid] * rsqrtf(var + EPSB);
            sm.e.ab[tid] = a;
            sm.e.ab[64 + tid] = be2[tid] - mean * a;
        }
        __syncthreads();
        if (tid < 64) {
            int pt = blk * 64 + tid;
            const float* row = ws + WS_POOL + (size_t)pt * CAT;
            float h[64];
#pragma unroll
            for (int c = 0; c < 64; c++) h[c] = sm.e.b3s[c];
            for (int j = 0; j < CAT; j++) {
                float pj = row[j];
#pragma unroll
                for (int c = 0; c < 64; c++) h[c] = fmaf(sm.e.W3t[j * 64 + c], pj, h[c]);
            }
#pragma unroll
            for (int c = 0; c < 64; c++)
                h[c] = fmaxf(0.f, fmaf(sm.e.ab[c], h[c], sm.e.ab[64 + c]));
            float* op = out + (size_t)pt * 64;
            for (int o = 0; o < 64; o += 4) {
                float a0 = sm.e.b4s[o], a1v = sm.e.b4s[o + 1];
                float a2v = sm.e.b4s[o + 2], a3v = sm.e.b4s[o + 3];
#pragma unroll
                for (int c = 0; c < 64; c++) {
                    float hv = h[c];
                    a0  = fmaf(sm.e.W4s[(o)     * 64 + c], hv, a0);
                    a1v = fmaf(sm.e.W4s[(o + 1) * 64 + c], hv, a1v);
                    a2v = fmaf(sm.e.W4s[(o + 2) * 64 + c], hv, a2v);
                    a3v = fmaf(sm.e.W4s[(o + 3) * 64 + c], hv, a3v);
                }
                *(float4*)(op + o) = make_float4(a0, a1v, a2v, a3v);
            }
        }
    }
}

extern "C" void kernel_launch(void* const* d_in, const int* in_sizes, int n_in,
                              void* d_out, int out_size, void* d_ws, size_t ws_size,
                              hipStream_t stream) {
    (void)in_sizes; (void)n_in; (void)out_size; (void)ws_size;
    const float* xin = (const float*)d_in[0];
    const float* W1  = (const float*)d_in[1];
    const float* b1  = (const float*)d_in[2];
    const float* g1  = (const float*)d_in[3];
    const float* be1 = (const float*)d_in[4];
    const float* W2  = (const float*)d_in[5];
    const float* b2  = (const float*)d_in[6];
    const float* W3  = (const float*)d_in[7];
    const float* b3  = (const float*)d_in[8];
    const float* g2  = (const float*)d_in[9];
    const float* be2 = (const float*)d_in[10];
    const float* W4  = (const float*)d_in[11];
    const float* b4  = (const float*)d_in[12];
    float* ws  = (float*)d_ws;
    float* out = (float*)d_out;

    hipMemsetAsync(d_ws, 0, 4096, stream);   // control lines + BN2/moment accumulators
    void* args[] = {
        (void*)&xin, (void*)&W1, (void*)&b1, (void*)&g1, (void*)&be1,
        (void*)&W2, (void*)&b2, (void*)&W3, (void*)&b3, (void*)&g2,
        (void*)&be2, (void*)&W4, (void*)&b4, (void*)&ws, (void*)&out
    };
    hipLaunchCooperativeKernel((const void*)fused, dim3(256), dim3(512),
                               args, 0, stream);
}

// Round 11
// 2116.258 us; speedup vs baseline: 1.0941x; 1.0941x over previous
//
#include <hip/hip_runtime.h>
#include <float.h>

#define BB   8
#define NN   4096
#define SS   2048
#define MID  32
#define COUT 64
#define CAT  67            // 3 + 64
#define M1   (BB*NN)       // 32768
#define M2   (BB*SS)       // 16384
#define EPSB 1e-5f
#define NCHUNK 64          // chunks per batch
#define CSZ    32          // centroids per chunk

// ---- control (int offsets; each hot word on its own 64B line) ----
#define I_B0   0
#define I_B1   16
#define I_B2   32
#define I_TKT  64
#define I_PROG 80          // + b*16
// ---- float offsets ----
#define WS_RED2  256                     // 128 floats BN2 sums (atomic)
#define WS_RED1  400                     // 64 x 9 moment partials
#define WS_FPS   1024                    // 16384 ints
#define WS_FEATS (1024 + 16384)          // 32768*64 floats
#define WS_POOL  (WS_FEATS + M1*COUT)    // 16384*67 floats

// ---- shared memory union (max = SC ~148 KB -> 1 block/CU) ----
struct SA  { float red[8][9]; };
struct SB4 { float4 Pc[NN]; alignas(16) unsigned long long sv[2][8];
             alignas(16) int fbuf[SS]; };
struct SB3 { float W1s[96]; float abv[64]; float W2s[2048]; float b2s[64]; float mom[9]; };
struct SC  { float4 Pq[NN]; unsigned long long cand[CSZ][257]; int fin[CSZ][16];
             float W3s[64 * CAT]; float b3s[64]; float ps[128]; int tkt; };
struct SE  { float W3t[CAT * 64]; float W4s[4096]; float b3s[64]; float b4s[64]; float ab[128]; };
union  SU  { SA a; SB4 b4; SB3 b3; SC c; SE e; };

__device__ __forceinline__ unsigned long long u64max(unsigned long long a,
                                                     unsigned long long b) {
    return a > b ? a : b;
}

template <int CTRL>
__device__ __forceinline__ unsigned long long dpp_swap_max(unsigned long long v) {
    int lo = (int)(unsigned)v;
    int hi = (int)(unsigned)(v >> 32);
    int olo = __builtin_amdgcn_update_dpp(0, lo, CTRL, 0xF, 0xF, false);
    int ohi = __builtin_amdgcn_update_dpp(0, hi, CTRL, 0xF, 0xF, false);
    unsigned long long ov = ((unsigned long long)(unsigned)ohi << 32) | (unsigned)olo;
    return u64max(v, ov);
}

// sleepy single-use device barrier; long sleep to keep its line cold
__device__ __forceinline__ void barrier_join(int* ctr, int target) {
    __syncthreads();
    if (threadIdx.x == 0) {
        __threadfence();
        atomicAdd(ctr, 1);
        while (__hip_atomic_load(ctr, __ATOMIC_RELAXED, __HIP_MEMORY_SCOPE_AGENT) < target)
            __builtin_amdgcn_s_sleep(64);
        __threadfence();
    }
    __syncthreads();
}

// keep smallest-16 u64 keys; cmaxv/cpos track current max slot
__device__ __forceinline__ void top16_insert(unsigned long long* cv,
                                             unsigned long long newv,
                                             unsigned long long& cmaxv, int& cpos) {
#pragma unroll
    for (int j = 0; j < 16; j++) cv[j] = (j == cpos) ? newv : cv[j];
    unsigned long long m1a[8]; int p1a[8];
#pragma unroll
    for (int j = 0; j < 8; j++) {
        bool s = cv[2 * j + 1] > cv[2 * j];
        m1a[j] = s ? cv[2 * j + 1] : cv[2 * j];
        p1a[j] = s ? 2 * j + 1 : 2 * j;
    }
    unsigned long long m2a[4]; int p2a[4];
#pragma unroll
    for (int j = 0; j < 4; j++) {
        bool s = m1a[2 * j + 1] > m1a[2 * j];
        m2a[j] = s ? m1a[2 * j + 1] : m1a[2 * j];
        p2a[j] = s ? p1a[2 * j + 1] : p1a[2 * j];
    }
    unsigned long long m3a, m3b; int p3a, p3b;
    { bool s = m2a[1] > m2a[0]; m3a = s ? m2a[1] : m2a[0]; p3a = s ? p2a[1] : p2a[0]; }
    { bool s = m2a[3] > m2a[2]; m3b = s ? m2a[3] : m2a[2]; p3b = s ? p2a[3] : p2a[2]; }
    bool s = m3b > m3a;
    cmaxv = s ? m3b : m3a; cpos = s ? p3b : p3a;
}

__global__ __launch_bounds__(512) void fused(
        const float* __restrict__ xin,
        const float* __restrict__ W1, const float* __restrict__ b1,
        const float* __restrict__ g1, const float* __restrict__ be1,
        const float* __restrict__ W2, const float* __restrict__ b2,
        const float* __restrict__ W3, const float* __restrict__ b3,
        const float* __restrict__ g2, const float* __restrict__ be2,
        const float* __restrict__ W4, const float* __restrict__ b4,
        float* __restrict__ ws, float* __restrict__ out) {
    __shared__ SU sm;
    int blk = blockIdx.x, tid = threadIdx.x;
    int* ctri  = (int*)ws;
    int* fidxg = (int*)(ws + WS_FPS);
    (void)b1;

    if (blk < 8) {
        //======== FPS producer: R9 reduce; LDS-staged publish every 32 ========
        int b = blk;
        const float* xb = xin + (size_t)b * NN * 3;
        int* fob = fidxg + b * SS;
        int* progb = ctri + I_PROG + b * 16;
        float px[8], py[8], pz[8], dist[8];
#pragma unroll
        for (int k = 0; k < 8; k++) {
            int i = tid + (k << 9);
            float x = xb[3 * i], y = xb[3 * i + 1], z = xb[3 * i + 2];
            px[k] = x; py[k] = y; pz[k] = z; dist[k] = FLT_MAX;
            sm.b4.Pc[i] = make_float4(x, y, z, 0.f);
        }
        if (tid == 0) sm.b4.fbuf[0] = 0;
        __syncthreads();
        float4 c0 = sm.b4.Pc[0];
        float cx = c0.x, cy = c0.y, cz = c0.z;
        int wid = tid >> 6, lane = tid & 63;
        for (int t = 1; t < SS; t++) {
            float bv = -1.f; int bi = 0;
#pragma unroll
            for (int k = 0; k < 8; k++) {
                float dx = px[k] - cx, dy = py[k] - cy, dz = pz[k] - cz;
                float d = fmaf(dz, dz, fmaf(dy, dy, dx * dx));
                float nd = fminf(dist[k], d);
                dist[k] = nd;
                bool bt = nd > bv;
                bv = bt ? nd : bv; bi = bt ? (tid + (k << 9)) : bi;
            }
            unsigned long long v =
                ((unsigned long long)__float_as_uint(bv) << 32) | (unsigned)(~bi);
            v = dpp_swap_max<0xB1>(v);
            v = dpp_swap_max<0x4E>(v);
            v = dpp_swap_max<0x141>(v);
            v = dpp_swap_max<0x140>(v);
            {
                int a16 = ((lane ^ 16) << 2), a32 = ((lane ^ 32) << 2), a48 = ((lane ^ 48) << 2);
                int lo = (int)(unsigned)v, hi = (int)(unsigned)(v >> 32);
                int lo16 = __builtin_amdgcn_ds_bpermute(a16, lo);
                int hi16 = __builtin_amdgcn_ds_bpermute(a16, hi);
                int lo32 = __builtin_amdgcn_ds_bpermute(a32, lo);
                int hi32 = __builtin_amdgcn_ds_bpermute(a32, hi);
                int lo48 = __builtin_amdgcn_ds_bpermute(a48, lo);
                int hi48 = __builtin_amdgcn_ds_bpermute(a48, hi);
                unsigned long long v16 = ((unsigned long long)(unsigned)hi16 << 32) | (unsigned)lo16;
                unsigned long long v32 = ((unsigned long long)(unsigned)hi32 << 32) | (unsigned)lo32;
                unsigned long long v48 = ((unsigned long long)(unsigned)hi48 << 32) | (unsigned)lo48;
                v = u64max(u64max(v, v16), u64max(v32, v48));
            }
            int par = t & 1;
            if (lane == 0) sm.b4.sv[par][wid] = v;
            __syncthreads();
            const ulonglong2* sp = (const ulonglong2*)sm.b4.sv[par];
            ulonglong2 q0 = sp[0], q1 = sp[1], q2 = sp[2], q3 = sp[3];
            unsigned long long m0 = u64max(q0.x, q0.y), m1 = u64max(q1.x, q1.y);
            unsigned long long m2 = u64max(q2.x, q2.y), m3 = u64max(q3.x, q3.y);
            unsigned long long best = u64max(u64max(m0, m1), u64max(m2, m3));
            int bsel = (int)(~(unsigned)best);
            float4 cc = sm.b4.Pc[bsel];
            cx = cc.x; cy = cc.y; cz = cc.z;
            if (tid == 0) {
                sm.b4.fbuf[t] = bsel;          // LDS only: no vmcnt in the loop
                if ((t & 31) == 31) {          // bulk publish 32 indices
                    int base = t - 31;
#pragma unroll
                    for (int g = 0; g < 8; g++) {
                        int4 vv = *(const int4*)(sm.b4.fbuf + base + g * 4);
                        *(int4*)(fob + base + g * 4) = vv;
                    }
                    __hip_atomic_store(progb, t + 1, __ATOMIC_RELEASE,
                                       __HIP_MEMORY_SCOPE_AGENT);
                }
            }
        }
        barrier_join(ctri + I_B2, 256);
    } else {
        //======== Phase A: BN1 moments (blocks 8-71) ========
        if (blk < 72) {
            int p = (blk - 8) * 512 + tid;
            float x0 = xin[3 * p], x1 = xin[3 * p + 1], x2 = xin[3 * p + 2];
            float r[9];
            r[0] = x0; r[1] = x1; r[2] = x2;
            r[3] = x0 * x0; r[4] = x0 * x1; r[5] = x0 * x2;
            r[6] = x1 * x1; r[7] = x1 * x2; r[8] = x2 * x2;
#pragma unroll
            for (int m = 32; m; m >>= 1) {
#pragma unroll
                for (int q = 0; q < 9; q++) r[q] += __shfl_down(r[q], m, 64);
            }
            if ((tid & 63) == 0) {
#pragma unroll
                for (int q = 0; q < 9; q++) sm.a.red[tid >> 6][q] = r[q];
            }
            __syncthreads();
            if (tid == 0) {
#pragma unroll
                for (int q = 0; q < 9; q++) {
                    float s = 0.f;
#pragma unroll
                    for (int w = 0; w < 8; w++) s += sm.a.red[w][q];
                    ws[WS_RED1 + (blk - 8) * 9 + q] = s;
                }
            }
            barrier_join(ctri + I_B0, 64);
            //======== feats = conv2(relu(bn(conv1))) ========
            for (int j = tid; j < 96; j += 512) sm.b3.W1s[j] = W1[j];
            if (tid < 64) sm.b3.b2s[tid] = b2[tid];
            for (int j = tid; j < 2048; j += 512) sm.b3.W2s[j] = W2[j];
            if (tid < 9) {
                float s = 0.f;
                for (int k = 0; k < 64; k++) s += ws[WS_RED1 + k * 9 + tid];
                sm.b3.mom[tid] = s;
            }
            __syncthreads();
            if (tid < MID) {
                float S0 = sm.b3.mom[0], S1 = sm.b3.mom[1], S2 = sm.b3.mom[2];
                float C00 = sm.b3.mom[3], C01 = sm.b3.mom[4], C02 = sm.b3.mom[5];
                float C11 = sm.b3.mom[6], C12 = sm.b3.mom[7], C22 = sm.b3.mom[8];
                float w0 = W1[3 * tid], w1 = W1[3 * tid + 1], w2 = W1[3 * tid + 2];
                float invM = 1.f / (float)M1;
                float meanc = (w0 * S0 + w1 * S1 + w2 * S2) * invM;
                float wCw = w0 * w0 * C00 + w1 * w1 * C11 + w2 * w2 * C22 +
                            2.f * (w0 * w1 * C01 + w0 * w2 * C02 + w1 * w2 * C12);
                float var = wCw * invM - meanc * meanc;
                float a = g1[tid] * rsqrtf(var + EPSB);
                sm.b3.abv[tid] = a;
                sm.b3.abv[MID + tid] = be1[tid] - meanc * a;
            }
            __syncthreads();
            int p2 = (blk - 8) * 512 + tid;
            float y0 = xin[3 * p2], y1 = xin[3 * p2 + 1], y2 = xin[3 * p2 + 2];
            float h[MID];
#pragma unroll
            for (int o = 0; o < MID; o++) {
                float y = fmaf(sm.b3.W1s[3 * o + 2], y2,
                         fmaf(sm.b3.W1s[3 * o + 1], y1, sm.b3.W1s[3 * o] * y0));
                h[o] = fmaxf(0.f, fmaf(sm.b3.abv[o], y, sm.b3.abv[MID + o]));
            }
            float* fo = ws + WS_FEATS + (size_t)p2 * COUT;
#pragma unroll
            for (int j = 0; j < COUT; j += 4) {
                float a0 = sm.b3.b2s[j], a1v = sm.b3.b2s[j + 1];
                float a2v = sm.b3.b2s[j + 2], a3v = sm.b3.b2s[j + 3];
#pragma unroll
                for (int o = 0; o < MID; o++) {
                    float hv = h[o];
                    a0  = fmaf(sm.b3.W2s[(j)     * MID + o], hv, a0);
                    a1v = fmaf(sm.b3.W2s[(j + 1) * MID + o], hv, a1v);
                    a2v = fmaf(sm.b3.W2s[(j + 2) * MID + o], hv, a2v);
                    a3v = fmaf(sm.b3.W2s[(j + 3) * MID + o], hv, a3v);
                }
                *(float4*)(fo + j) = make_float4(a0, a1v, a2v, a3v);
            }
        }
        barrier_join(ctri + I_B1, 248);   // feats visible to all consumers

        //======== consumer: load W3 once, then ticket loop w/ fused BN2 ========
        for (int j = tid; j < 64 * CAT; j += 512) sm.c.W3s[j] = W3[j];
        if (tid < 64) sm.c.b3s[tid] = b3[tid];
        if (tid < 128) sm.c.ps[tid] = 0.f;
        __syncthreads();
        int c0ch = (tid & 15) * 4;                      // 4 BN2 channels per thread
        float bsum[4] = {0.f, 0.f, 0.f, 0.f}, bsq[4] = {0.f, 0.f, 0.f, 0.f};
        int curb = -1;
        for (;;) {
            if (tid == 0) sm.c.tkt = atomicAdd(ctri + I_TKT, 1);
            __syncthreads();
            int tk = sm.c.tkt;
            if (tk >= BB * NCHUNK) break;
            int b = tk & 7, c = tk >> 3;
            if (b != curb) {
                const float* xb = xin + (size_t)b * NN * 3;
                for (int j = tid; j < NN; j += 512) {
                    float x = xb[3 * j], y = xb[3 * j + 1], z = xb[3 * j + 2];
                    sm.c.Pq[j] = make_float4(x, y, z, (x * x + y * y) + z * z);
                }
                curb = b;
            }
            if (tid == 0) {               // wait for FPS prefix (cold polling)
                int* progb = ctri + I_PROG + b * 16;
                int need = (c + 1) * CSZ;
                while (__hip_atomic_load(progb, __ATOMIC_RELAXED,
                                         __HIP_MEMORY_SCOPE_AGENT) < need)
                    __builtin_amdgcn_s_sleep(64);
                (void)__hip_atomic_load(progb, __ATOMIC_ACQUIRE,
                                        __HIP_MEMORY_SCOPE_AGENT);
            }
            __syncthreads();
            int cc = tid >> 4, q = tid & 15;   // 32 centroids x 16 lanes
            int s = c * CSZ + cc;
            int sg = b * SS + s;
            int ci = fidxg[sg];
            float4 cen = sm.c.Pq[ci];
            float an = cen.w;
            unsigned long long cv[16];
#pragma unroll
            for (int j = 0; j < 16; j++) cv[j] = ~0ULL;
            unsigned long long cmaxv = ~0ULL; int cpos = 0;
            for (int n0 = 0; n0 < 256; n0++) {
                int n = (q << 8) + ((n0 + q) & 255);
                float4 qq = sm.c.Pq[n];
                float dot = fmaf(cen.z, qq.z, fmaf(cen.y, qq.y, cen.x * qq.x));
                float dd = (an + qq.w) - 2.f * dot;
                unsigned db = __float_as_uint(dd);
                db ^= (unsigned)(((int)db >> 31) | 0x80000000u);
                unsigned long long newv = ((unsigned long long)db << 32) | (unsigned)n;
                if (newv < cmaxv) top16_insert(cv, newv, cmaxv, cpos);
            }
#pragma unroll
            for (int j = 0; j < 16; j++)         // (j+q)&15: break 128B bank alias
                sm.c.cand[cc][q * 16 + ((j + q) & 15)] = cv[j];
            __syncthreads();
            if (tid < CSZ) {              // merge 256 -> 16 per centroid
                unsigned long long mv[16];
#pragma unroll
                for (int j = 0; j < 16; j++) mv[j] = ~0ULL;
                unsigned long long mx = ~0ULL; int mp = 0;
                for (int k = 0; k < 256; k++) {
                    unsigned long long e = sm.c.cand[tid][k];
                    if (e < mx) top16_insert(mv, e, mx, mp);
                }
#pragma unroll
                for (int j = 0; j < 16; j++) sm.c.fin[tid][j] = (int)(unsigned)mv[j];
            }
            __syncthreads();
            int idxs[16];
#pragma unroll
            for (int j = 0; j < 16; j++) idxs[j] = sm.c.fin[cc][j];
            const float* feats = ws + WS_FEATS + (size_t)b * NN * COUT;
            float4 acc = make_float4(-FLT_MAX, -FLT_MAX, -FLT_MAX, -FLT_MAX);
#pragma unroll 4
            for (int k = 0; k < 16; k++) {
                const float4* fp = (const float4*)(feats + (size_t)idxs[k] * COUT) + q;
                float4 v0 = fp[0];
                acc.x = fmaxf(acc.x, v0.x); acc.y = fmaxf(acc.y, v0.y);
                acc.z = fmaxf(acc.z, v0.z); acc.w = fmaxf(acc.w, v0.w);
            }
            float* po = ws + WS_POOL + (size_t)sg * CAT;
            po[3 + q * 4] = acc.x; po[4 + q * 4] = acc.y;
            po[5 + q * 4] = acc.z; po[6 + q * 4] = acc.w;
            if (q == 0) {
                float rx = -FLT_MAX, ry = -FLT_MAX, rz = -FLT_MAX;
#pragma unroll
                for (int k = 0; k < 16; k++) {
                    float4 p = sm.c.Pq[idxs[k]];
                    rx = fmaxf(rx, p.x - cen.x);
                    ry = fmaxf(ry, p.y - cen.y);
                    rz = fmaxf(rz, p.z - cen.z);
                }
                po[0] = rx; po[1] = ry; po[2] = rz;
            }
            __syncthreads();              // all 16 q-lanes wrote the row
            // fused BN2 partial: row (c*32 + tid>>4), channels c0ch..+3
            {
                int rrow = b * SS + c * CSZ + (tid >> 4);
                const float* rp = ws + WS_POOL + (size_t)rrow * CAT;
                float y0 = sm.c.b3s[c0ch],     y1 = sm.c.b3s[c0ch + 1];
                float y2 = sm.c.b3s[c0ch + 2], y3 = sm.c.b3s[c0ch + 3];
                for (int j = 0; j < CAT; j++) {
                    float pj = rp[j];
                    y0 = fmaf(sm.c.W3s[(c0ch)     * CAT + j], pj, y0);
                    y1 = fmaf(sm.c.W3s[(c0ch + 1) * CAT + j], pj, y1);
                    y2 = fmaf(sm.c.W3s[(c0ch + 2) * CAT + j], pj, y2);
                    y3 = fmaf(sm.c.W3s[(c0ch + 3) * CAT + j], pj, y3);
                }
                bsum[0] += y0; bsq[0] = fmaf(y0, y0, bsq[0]);
                bsum[1] += y1; bsq[1] = fmaf(y1, y1, bsq[1]);
                bsum[2] += y2; bsq[2] = fmaf(y2, y2, bsq[2]);
                bsum[3] += y3; bsq[3] = fmaf(y3, y3, bsq[3]);
            }
        }
        // flush BN2 partials: LDS reduce then 128 global atomics
#pragma unroll
        for (int u = 0; u < 4; u++) {
            atomicAdd(&sm.c.ps[c0ch + u], bsum[u]);
            atomicAdd(&sm.c.ps[64 + c0ch + u], bsq[u]);
        }
        __syncthreads();
        if (tid < 128) atomicAdd(ws + WS_RED2 + tid, sm.c.ps[tid]);
        barrier_join(ctri + I_B2, 256);
    }

    //======== D: final MLP (all 256 blocks, 64 rows each) ========
    {
        for (int lin = tid; lin < CAT * 64; lin += 512) {
            int j = lin >> 6, o = lin & 63;
            sm.e.W3t[lin] = W3[o * CAT + j];
        }
        for (int j = tid; j < 4096; j += 512) sm.e.W4s[j] = W4[j];
        if (tid < 64) {
            sm.e.b3s[tid] = b3[tid]; sm.e.b4s[tid] = b4[tid];
            float inv = 1.f / (float)M2;
            float mean = ws[WS_RED2 + tid] * inv;
            float var = ws[WS_RED2 + 64 + tid] * inv - mean * mean;
            float a = g2[tid] * rsqrtf(var + EPSB);
            sm.e.ab[tid] = a;
            sm.e.ab[64 + tid] = be2[tid] - mean * a;
        }
        __syncthreads();
        if (tid < 64) {
            int pt = blk * 64 + tid;
            const float* row = ws + WS_POOL + (size_t)pt * CAT;
            float h[64];
#pragma unroll
            for (int c = 0; c < 64; c++) h[c] = sm.e.b3s[c];
            for (int j = 0; j < CAT; j++) {
                float pj = row[j];
#pragma unroll
                for (int c = 0; c < 64; c++) h[c] = fmaf(sm.e.W3t[j * 64 + c], pj, h[c]);
            }
#pragma unroll
            for (int c = 0; c < 64; c++)
                h[c] = fmaxf(0.f, fmaf(sm.e.ab[c], h[c], sm.e.ab[64 + c]));
            float* op = out + (size_t)pt * 64;
            for (int o = 0; o < 64; o += 4) {
                float a0 = sm.e.b4s[o], a1v = sm.e.b4s[o + 1];
                float a2v = sm.e.b4s[o + 2], a3v = sm.e.b4s[o + 3];
#pragma unroll
                for (int c = 0; c < 64; c++) {
                    float hv = h[c];
                    a0  = fmaf(sm.e.W4s[(o)     * 64 + c], hv, a0);
                    a1v = fmaf(sm.e.W4s[(o + 1) * 64 + c], hv, a1v);
                    a2v = fmaf(sm.e.W4s[(o + 2) * 64 + c], hv, a2v);
                    a3v = fmaf(sm.e.W4s[(o + 3) * 64 + c], hv, a3v);
                }
                *(float4*)(op + o) = make_float4(a0, a1v, a2v, a3v);
            }
        }
    }
}

extern "C" void kernel_launch(void* const* d_in, const int* in_sizes, int n_in,
                              void* d_out, int out_size, void* d_ws, size_t ws_size,
                              hipStream_t stream) {
    (void)in_sizes; (void)n_in; (void)out_size; (void)ws_size;
    const float* xin = (const float*)d_in[0];
    const float* W1  = (const float*)d_in[1];
    const float* b1  = (const float*)d_in[2];
    const float* g1  = (const float*)d_in[3];
    const float* be1 = (const float*)d_in[4];
    const float* W2  = (const float*)d_in[5];
    const float* b2  = (const float*)d_in[6];
    const float* W3  = (const float*)d_in[7];
    const float* b3  = (const float*)d_in[8];
    const float* g2  = (const float*)d_in[9];
    const float* be2 = (const float*)d_in[10];
    const float* W4  = (const float*)d_in[11];
    const float* b4  = (const float*)d_in[12];
    float* ws  = (float*)d_ws;
    float* out = (float*)d_out;

    hipMemsetAsync(d_ws, 0, 4096, stream);   // control lines + BN2/moment accumulators
    void* args[] = {
        (void*)&xin, (void*)&W1, (void*)&b1, (void*)&g1, (void*)&be1,
        (void*)&W2, (void*)&b2, (void*)&W3, (void*)&b3, (void*)&g2,
        (void*)&be2, (void*)&W4, (void*)&b4, (void*)&ws, (void*)&out
    };
    hipLaunchCooperativeKernel((const void*)fused, dim3(256), dim3(512),
                               args, 0, stream);
}

// Round 12
// 2078.517 us; speedup vs baseline: 1.1140x; 1.0182x over previous
//
#include <hip/hip_runtime.h>
#include <float.h>

#define BB   8
#define NN   4096
#define SS   2048
#define MID  32
#define COUT 64
#define CAT  67            // 3 + 64
#define M1   (BB*NN)       // 32768
#define M2   (BB*SS)       // 16384
#define EPSB 1e-5f
#define NCHUNK 64          // chunks per batch
#define CSZ    32          // centroids per chunk

// ---- control (int offsets; each hot word on its own 64B line) ----
#define I_B0   0
#define I_B1   16
#define I_B2   32
#define I_TKT  64
#define I_PROG 80          // + b*16
// ---- float offsets ----
#define WS_RED2  256                     // 128 floats BN2 sums (atomic)
#define WS_RED1  400                     // 64 x 9 moment partials
#define WS_FPS   1024                    // 16384 ints
#define WS_FEATS (1024 + 16384)          // 32768*64 floats
#define WS_POOL  (WS_FEATS + M1*COUT)    // 16384*67 floats

// ---- shared memory union (max = SC ~148 KB -> 1 block/CU) ----
struct SA  { float red[8][9]; };
struct SB4 { float4 Pc[NN]; alignas(16) unsigned long long sv[2][8]; };
struct SB3 { float W1s[96]; float abv[64]; float W2s[2048]; float b2s[64]; float mom[9]; };
struct SC  { float4 Pq[NN]; unsigned long long cand[CSZ][257]; int fin[CSZ][16];
             float W3s[64 * CAT]; float b3s[64]; float ps[128]; int tkt; };
struct SE  { float W3se[64 * CAT]; float W4s[4096]; float hbuf[64][64];
             float b3s[64]; float b4s[64]; float ab[128]; };
union  SU  { SA a; SB4 b4; SB3 b3; SC c; SE e; };

__device__ __forceinline__ unsigned long long u64max(unsigned long long a,
                                                     unsigned long long b) {
    return a > b ? a : b;
}

template <int CTRL>
__device__ __forceinline__ unsigned long long dpp_swap_max(unsigned long long v) {
    int lo = (int)(unsigned)v;
    int hi = (int)(unsigned)(v >> 32);
    int olo = __builtin_amdgcn_update_dpp(0, lo, CTRL, 0xF, 0xF, false);
    int ohi = __builtin_amdgcn_update_dpp(0, hi, CTRL, 0xF, 0xF, false);
    unsigned long long ov = ((unsigned long long)(unsigned)ohi << 32) | (unsigned)olo;
    return u64max(v, ov);
}

// sleepy single-use device barrier; long sleep to keep its line cold
__device__ __forceinline__ void barrier_join(int* ctr, int target) {
    __syncthreads();
    if (threadIdx.x == 0) {
        __threadfence();
        atomicAdd(ctr, 1);
        while (__hip_atomic_load(ctr, __ATOMIC_RELAXED, __HIP_MEMORY_SCOPE_AGENT) < target)
            __builtin_amdgcn_s_sleep(64);
        __threadfence();
    }
    __syncthreads();
}

// keep smallest-16 u64 keys; cmaxv/cpos track current max slot
__device__ __forceinline__ void top16_insert(unsigned long long* cv,
                                             unsigned long long newv,
                                             unsigned long long& cmaxv, int& cpos) {
#pragma unroll
    for (int j = 0; j < 16; j++) cv[j] = (j == cpos) ? newv : cv[j];
    unsigned long long m1a[8]; int p1a[8];
#pragma unroll
    for (int j = 0; j < 8; j++) {
        bool s = cv[2 * j + 1] > cv[2 * j];
        m1a[j] = s ? cv[2 * j + 1] : cv[2 * j];
        p1a[j] = s ? 2 * j + 1 : 2 * j;
    }
    unsigned long long m2a[4]; int p2a[4];
#pragma unroll
    for (int j = 0; j < 4; j++) {
        bool s = m1a[2 * j + 1] > m1a[2 * j];
        m2a[j] = s ? m1a[2 * j + 1] : m1a[2 * j];
        p2a[j] = s ? p1a[2 * j + 1] : p1a[2 * j];
    }
    unsigned long long m3a, m3b; int p3a, p3b;
    { bool s = m2a[1] > m2a[0]; m3a = s ? m2a[1] : m2a[0]; p3a = s ? p2a[1] : p2a[0]; }
    { bool s = m2a[3] > m2a[2]; m3b = s ? m2a[3] : m2a[2]; p3b = s ? p2a[3] : p2a[2]; }
    bool s = m3b > m3a;
    cmaxv = s ? m3b : m3a; cpos = s ? p3b : p3a;
}

__global__ __launch_bounds__(512) void fused(
        const float* __restrict__ xin,
        const float* __restrict__ W1, const float* __restrict__ b1,
        const float* __restrict__ g1, const float* __restrict__ be1,
        const float* __restrict__ W2, const float* __restrict__ b2,
        const float* __restrict__ W3, const float* __restrict__ b3,
        const float* __restrict__ g2, const float* __restrict__ be2,
        const float* __restrict__ W4, const float* __restrict__ b4,
        float* __restrict__ ws, float* __restrict__ out) {
    __shared__ SU sm;
    int blk = blockIdx.x, tid = threadIdx.x;
    int* ctri  = (int*)ws;
    int* fidxg = (int*)(ws + WS_FPS);
    (void)b1;

    if (blk < 8) {
        //======== FPS producer (R9-exact): DPP+bpermute reduce, rbuf publish ========
        int b = blk;
        const float* xb = xin + (size_t)b * NN * 3;
        int* fob = fidxg + b * SS;
        int* progb = ctri + I_PROG + b * 16;
        float px[8], py[8], pz[8], dist[8];
#pragma unroll
        for (int k = 0; k < 8; k++) {
            int i = tid + (k << 9);
            float x = xb[3 * i], y = xb[3 * i + 1], z = xb[3 * i + 2];
            px[k] = x; py[k] = y; pz[k] = z; dist[k] = FLT_MAX;
            sm.b4.Pc[i] = make_float4(x, y, z, 0.f);
        }
        __syncthreads();
        float4 c0 = sm.b4.Pc[0];
        float cx = c0.x, cy = c0.y, cz = c0.z;
        int wid = tid >> 6, lane = tid & 63;
        int rbuf[8];
        rbuf[0] = 0;                       // fidx[0] = 0
        for (int t = 1; t < SS; t++) {
            float bv = -1.f; int bi = 0;
#pragma unroll
            for (int k = 0; k < 8; k++) {
                float dx = px[k] - cx, dy = py[k] - cy, dz = pz[k] - cz;
                float d = fmaf(dz, dz, fmaf(dy, dy, dx * dx));
                float nd = fminf(dist[k], d);
                dist[k] = nd;
                bool bt = nd > bv;
                bv = bt ? nd : bv; bi = bt ? (tid + (k << 9)) : bi;
            }
            unsigned long long v =
                ((unsigned long long)__float_as_uint(bv) << 32) | (unsigned)(~bi);
            v = dpp_swap_max<0xB1>(v);
            v = dpp_swap_max<0x4E>(v);
            v = dpp_swap_max<0x141>(v);
            v = dpp_swap_max<0x140>(v);
            {
                int a16 = ((lane ^ 16) << 2), a32 = ((lane ^ 32) << 2), a48 = ((lane ^ 48) << 2);
                int lo = (int)(unsigned)v, hi = (int)(unsigned)(v >> 32);
                int lo16 = __builtin_amdgcn_ds_bpermute(a16, lo);
                int hi16 = __builtin_amdgcn_ds_bpermute(a16, hi);
                int lo32 = __builtin_amdgcn_ds_bpermute(a32, lo);
                int hi32 = __builtin_amdgcn_ds_bpermute(a32, hi);
                int lo48 = __builtin_amdgcn_ds_bpermute(a48, lo);
                int hi48 = __builtin_amdgcn_ds_bpermute(a48, hi);
                unsigned long long v16 = ((unsigned long long)(unsigned)hi16 << 32) | (unsigned)lo16;
                unsigned long long v32 = ((unsigned long long)(unsigned)hi32 << 32) | (unsigned)lo32;
                unsigned long long v48 = ((unsigned long long)(unsigned)hi48 << 32) | (unsigned)lo48;
                v = u64max(u64max(v, v16), u64max(v32, v48));
            }
            int par = t & 1;
            if (lane == 0) sm.b4.sv[par][wid] = v;
            __syncthreads();
            const ulonglong2* sp = (const ulonglong2*)sm.b4.sv[par];
            ulonglong2 q0 = sp[0], q1 = sp[1], q2 = sp[2], q3 = sp[3];
            unsigned long long m0 = u64max(q0.x, q0.y), m1 = u64max(q1.x, q1.y);
            unsigned long long m2 = u64max(q2.x, q2.y), m3 = u64max(q3.x, q3.y);
            unsigned long long best = u64max(u64max(m0, m1), u64max(m2, m3));
            int bsel = (int)(~(unsigned)best);
            float4 cc = sm.b4.Pc[bsel];
            cx = cc.x; cy = cc.y; cz = cc.z;
            if (tid == 0) {
                rbuf[t & 7] = bsel;
                if ((t & 7) == 7) {
                    *(int4*)(fob + t - 7) = make_int4(rbuf[0], rbuf[1], rbuf[2], rbuf[3]);
                    *(int4*)(fob + t - 3) = make_int4(rbuf[4], rbuf[5], rbuf[6], rbuf[7]);
                    if ((t & 31) == 31)
                        __hip_atomic_store(progb, t + 1, __ATOMIC_RELEASE,
                                           __HIP_MEMORY_SCOPE_AGENT);
                }
            }
        }
        barrier_join(ctri + I_B2, 256);
    } else {
        //======== Phase A: BN1 moments (blocks 8-71) ========
        if (blk < 72) {
            int p = (blk - 8) * 512 + tid;
            float x0 = xin[3 * p], x1 = xin[3 * p + 1], x2 = xin[3 * p + 2];
            float r[9];
            r[0] = x0; r[1] = x1; r[2] = x2;
            r[3] = x0 * x0; r[4] = x0 * x1; r[5] = x0 * x2;
            r[6] = x1 * x1; r[7] = x1 * x2; r[8] = x2 * x2;
#pragma unroll
            for (int m = 32; m; m >>= 1) {
#pragma unroll
                for (int q = 0; q < 9; q++) r[q] += __shfl_down(r[q], m, 64);
            }
            if ((tid & 63) == 0) {
#pragma unroll
                for (int q = 0; q < 9; q++) sm.a.red[tid >> 6][q] = r[q];
            }
            __syncthreads();
            if (tid == 0) {
#pragma unroll
                for (int q = 0; q < 9; q++) {
                    float s = 0.f;
#pragma unroll
                    for (int w = 0; w < 8; w++) s += sm.a.red[w][q];
                    ws[WS_RED1 + (blk - 8) * 9 + q] = s;
                }
            }
            barrier_join(ctri + I_B0, 64);
            //======== feats = conv2(relu(bn(conv1))) ========
            for (int j = tid; j < 96; j += 512) sm.b3.W1s[j] = W1[j];
            if (tid < 64) sm.b3.b2s[tid] = b2[tid];
            for (int j = tid; j < 2048; j += 512) sm.b3.W2s[j] = W2[j];
            if (tid < 9) {
                float s = 0.f;
                for (int k = 0; k < 64; k++) s += ws[WS_RED1 + k * 9 + tid];
                sm.b3.mom[tid] = s;
            }
            __syncthreads();
            if (tid < MID) {
                float S0 = sm.b3.mom[0], S1 = sm.b3.mom[1], S2 = sm.b3.mom[2];
                float C00 = sm.b3.mom[3], C01 = sm.b3.mom[4], C02 = sm.b3.mom[5];
                float C11 = sm.b3.mom[6], C12 = sm.b3.mom[7], C22 = sm.b3.mom[8];
                float w0 = W1[3 * tid], w1 = W1[3 * tid + 1], w2 = W1[3 * tid + 2];
                float invM = 1.f / (float)M1;
                float meanc = (w0 * S0 + w1 * S1 + w2 * S2) * invM;
                float wCw = w0 * w0 * C00 + w1 * w1 * C11 + w2 * w2 * C22 +
                            2.f * (w0 * w1 * C01 + w0 * w2 * C02 + w1 * w2 * C12);
                float var = wCw * invM - meanc * meanc;
                float a = g1[tid] * rsqrtf(var + EPSB);
                sm.b3.abv[tid] = a;
                sm.b3.abv[MID + tid] = be1[tid] - meanc * a;
            }
            __syncthreads();
            int p2 = (blk - 8) * 512 + tid;
            float y0 = xin[3 * p2], y1 = xin[3 * p2 + 1], y2 = xin[3 * p2 + 2];
            float h[MID];
#pragma unroll
            for (int o = 0; o < MID; o++) {
                float y = fmaf(sm.b3.W1s[3 * o + 2], y2,
                         fmaf(sm.b3.W1s[3 * o + 1], y1, sm.b3.W1s[3 * o] * y0));
                h[o] = fmaxf(0.f, fmaf(sm.b3.abv[o], y, sm.b3.abv[MID + o]));
            }
            float* fo = ws + WS_FEATS + (size_t)p2 * COUT;
#pragma unroll
            for (int j = 0; j < COUT; j += 4) {
                float a0 = sm.b3.b2s[j], a1v = sm.b3.b2s[j + 1];
                float a2v = sm.b3.b2s[j + 2], a3v = sm.b3.b2s[j + 3];
#pragma unroll
                for (int o = 0; o < MID; o++) {
                    float hv = h[o];
                    a0  = fmaf(sm.b3.W2s[(j)     * MID + o], hv, a0);
                    a1v = fmaf(sm.b3.W2s[(j + 1) * MID + o], hv, a1v);
                    a2v = fmaf(sm.b3.W2s[(j + 2) * MID + o], hv, a2v);
                    a3v = fmaf(sm.b3.W2s[(j + 3) * MID + o], hv, a3v);
                }
                *(float4*)(fo + j) = make_float4(a0, a1v, a2v, a3v);
            }
        }
        barrier_join(ctri + I_B1, 248);   // feats visible to all consumers

        //======== consumer: load W3 once, then ticket loop w/ fused BN2 ========
        for (int j = tid; j < 64 * CAT; j += 512) sm.c.W3s[j] = W3[j];
        if (tid < 64) sm.c.b3s[tid] = b3[tid];
        if (tid < 128) sm.c.ps[tid] = 0.f;
        __syncthreads();
        int c0ch = (tid & 15) * 4;                      // 4 BN2 channels per thread
        float bsum[4] = {0.f, 0.f, 0.f, 0.f}, bsq[4] = {0.f, 0.f, 0.f, 0.f};
        int curb = -1;
        for (;;) {
            if (tid == 0) sm.c.tkt = atomicAdd(ctri + I_TKT, 1);
            __syncthreads();
            int tk = sm.c.tkt;
            if (tk >= BB * NCHUNK) break;
            int b = tk & 7, c = tk >> 3;
            if (b != curb) {
                const float* xb = xin + (size_t)b * NN * 3;
                for (int j = tid; j < NN; j += 512) {
                    float x = xb[3 * j], y = xb[3 * j + 1], z = xb[3 * j + 2];
                    sm.c.Pq[j] = make_float4(x, y, z, (x * x + y * y) + z * z);
                }
                curb = b;
            }
            if (tid == 0) {               // wait for FPS prefix (cold polling)
                int* progb = ctri + I_PROG + b * 16;
                int need = (c + 1) * CSZ;
                while (__hip_atomic_load(progb, __ATOMIC_RELAXED,
                                         __HIP_MEMORY_SCOPE_AGENT) < need)
                    __builtin_amdgcn_s_sleep(64);
                (void)__hip_atomic_load(progb, __ATOMIC_ACQUIRE,
                                        __HIP_MEMORY_SCOPE_AGENT);
            }
            __syncthreads();
            int cc = tid >> 4, q = tid & 15;   // 32 centroids x 16 lanes
            int s = c * CSZ + cc;
            int sg = b * SS + s;
            int ci = fidxg[sg];
            float4 cen = sm.c.Pq[ci];
            float an = cen.w;
            unsigned long long cv[16];
#pragma unroll
            for (int j = 0; j < 16; j++) cv[j] = ~0ULL;
            unsigned long long cmaxv = ~0ULL; int cpos = 0;
            for (int n0 = 0; n0 < 256; n0++) {
                int n = (q << 8) + ((n0 + q) & 255);
                float4 qq = sm.c.Pq[n];
                float dot = fmaf(cen.z, qq.z, fmaf(cen.y, qq.y, cen.x * qq.x));
                float dd = (an + qq.w) - 2.f * dot;
                unsigned db = __float_as_uint(dd);
                db ^= (unsigned)(((int)db >> 31) | 0x80000000u);
                unsigned long long newv = ((unsigned long long)db << 32) | (unsigned)n;
                if (newv < cmaxv) top16_insert(cv, newv, cmaxv, cpos);
            }
#pragma unroll
            for (int j = 0; j < 16; j++)         // (j+q)&15: break 128B bank alias
                sm.c.cand[cc][q * 16 + ((j + q) & 15)] = cv[j];
            __syncthreads();
            if (tid < CSZ) {              // merge 256 -> 16 per centroid
                unsigned long long mv[16];
#pragma unroll
                for (int j = 0; j < 16; j++) mv[j] = ~0ULL;
                unsigned long long mx = ~0ULL; int mp = 0;
                for (int k = 0; k < 256; k++) {
                    unsigned long long e = sm.c.cand[tid][k];
                    if (e < mx) top16_insert(mv, e, mx, mp);
                }
#pragma unroll
                for (int j = 0; j < 16; j++) sm.c.fin[tid][j] = (int)(unsigned)mv[j];
            }
            __syncthreads();
            int idxs[16];
#pragma unroll
            for (int j = 0; j < 16; j++) idxs[j] = sm.c.fin[cc][j];
            const float* feats = ws + WS_FEATS + (size_t)b * NN * COUT;
            float4 acc = make_float4(-FLT_MAX, -FLT_MAX, -FLT_MAX, -FLT_MAX);
#pragma unroll 4
            for (int k = 0; k < 16; k++) {
                const float4* fp = (const float4*)(feats + (size_t)idxs[k] * COUT) + q;
                float4 v0 = fp[0];
                acc.x = fmaxf(acc.x, v0.x); acc.y = fmaxf(acc.y, v0.y);
                acc.z = fmaxf(acc.z, v0.z); acc.w = fmaxf(acc.w, v0.w);
            }
            float* po = ws + WS_POOL + (size_t)sg * CAT;
            po[3 + q * 4] = acc.x; po[4 + q * 4] = acc.y;
            po[5 + q * 4] = acc.z; po[6 + q * 4] = acc.w;
            if (q == 0) {
                float rx = -FLT_MAX, ry = -FLT_MAX, rz = -FLT_MAX;
#pragma unroll
                for (int k = 0; k < 16; k++) {
                    float4 p = sm.c.Pq[idxs[k]];
                    rx = fmaxf(rx, p.x - cen.x);
                    ry = fmaxf(ry, p.y - cen.y);
                    rz = fmaxf(rz, p.z - cen.z);
                }
                po[0] = rx; po[1] = ry; po[2] = rz;
            }
            __syncthreads();              // all 16 q-lanes wrote the row
            // fused BN2 partial: row (c*32 + tid>>4), channels c0ch..+3
            {
                int rrow = b * SS + c * CSZ + (tid >> 4);
                const float* rp = ws + WS_POOL + (size_t)rrow * CAT;
                float y0 = sm.c.b3s[c0ch],     y1 = sm.c.b3s[c0ch + 1];
                float y2 = sm.c.b3s[c0ch + 2], y3 = sm.c.b3s[c0ch + 3];
                for (int j = 0; j < CAT; j++) {
                    float pj = rp[j];
                    y0 = fmaf(sm.c.W3s[(c0ch)     * CAT + j], pj, y0);
                    y1 = fmaf(sm.c.W3s[(c0ch + 1) * CAT + j], pj, y1);
                    y2 = fmaf(sm.c.W3s[(c0ch + 2) * CAT + j], pj, y2);
                    y3 = fmaf(sm.c.W3s[(c0ch + 3) * CAT + j], pj, y3);
                }
                bsum[0] += y0; bsq[0] = fmaf(y0, y0, bsq[0]);
                bsum[1] += y1; bsq[1] = fmaf(y1, y1, bsq[1]);
                bsum[2] += y2; bsq[2] = fmaf(y2, y2, bsq[2]);
                bsum[3] += y3; bsq[3] = fmaf(y3, y3, bsq[3]);
            }
        }
        // flush BN2 partials: LDS reduce then 128 global atomics
#pragma unroll
        for (int u = 0; u < 4; u++) {
            atomicAdd(&sm.c.ps[c0ch + u], bsum[u]);
            atomicAdd(&sm.c.ps[64 + c0ch + u], bsq[u]);
        }
        __syncthreads();
        if (tid < 128) atomicAdd(ws + WS_RED2 + tid, sm.c.ps[tid]);
        barrier_join(ctri + I_B2, 256);
    }

    //======== D: final MLP (all 512 threads: 8 threads per row) ========
    {
        for (int j = tid; j < 64 * CAT; j += 512) sm.e.W3se[j] = W3[j];
        for (int j = tid; j < 4096; j += 512) sm.e.W4s[j] = W4[j];
        if (tid < 64) {
            sm.e.b3s[tid] = b3[tid]; sm.e.b4s[tid] = b4[tid];
            float inv = 1.f / (float)M2;
            float mean = ws[WS_RED2 + tid] * inv;
            float var = ws[WS_RED2 + 64 + tid] * inv - mean * mean;
            float a = g2[tid] * rsqrtf(var + EPSB);
            sm.e.ab[tid] = a;
            sm.e.ab[64 + tid] = be2[tid] - mean * a;
        }
        __syncthreads();
        int r = tid >> 3, p8 = tid & 7;           // 64 rows x 8 thread-slices
        int pt = blk * 64 + r;
        const float* row = ws + WS_POOL + (size_t)pt * CAT;
        float pv[CAT];
#pragma unroll
        for (int j = 0; j < CAT; j++) pv[j] = row[j];
        // conv3 slice: channels p8*8 .. p8*8+7, then BN+ReLU into LDS hbuf
        {
            float hh[8];
#pragma unroll
            for (int u = 0; u < 8; u++) hh[u] = sm.e.b3s[p8 * 8 + u];
#pragma unroll
            for (int u = 0; u < 8; u++) {
                int ch = p8 * 8 + u;
                float y = hh[u];
                for (int j = 0; j < CAT; j++)
                    y = fmaf(sm.e.W3se[ch * CAT + j], pv[j], y);
                hh[u] = fmaxf(0.f, fmaf(sm.e.ab[ch], y, sm.e.ab[64 + ch]));
            }
#pragma unroll
            for (int u = 0; u < 8; u++) sm.e.hbuf[r][p8 * 8 + u] = hh[u];
        }
        __syncthreads();
        // conv4 slice: outputs p8*8 .. p8*8+7 for row r
        {
            float hr[64];
#pragma unroll
            for (int c2 = 0; c2 < 64; c2++) hr[c2] = sm.e.hbuf[r][c2];
            float o0[8];
#pragma unroll
            for (int u = 0; u < 8; u++) {
                int oc = p8 * 8 + u;
                float y = sm.e.b4s[oc];
#pragma unroll
                for (int c2 = 0; c2 < 64; c2++)
                    y = fmaf(sm.e.W4s[oc * 64 + c2], hr[c2], y);
                o0[u] = y;
            }
            float* op = out + (size_t)pt * 64 + p8 * 8;
            *(float4*)(op)     = make_float4(o0[0], o0[1], o0[2], o0[3]);
            *(float4*)(op + 4) = make_float4(o0[4], o0[5], o0[6], o0[7]);
        }
    }
}

extern "C" void kernel_launch(void* const* d_in, const int* in_sizes, int n_in,
                              void* d_out, int out_size, void* d_ws, size_t ws_size,
                              hipStream_t stream) {
    (void)in_sizes; (void)n_in; (void)out_size; (void)ws_size;
    const float* xin = (const float*)d_in[0];
    const float* W1  = (const float*)d_in[1];
    const float* b1  = (const float*)d_in[2];
    const float* g1  = (const float*)d_in[3];
    const float* be1 = (const float*)d_in[4];
    const float* W2  = (const float*)d_in[5];
    const float* b2  = (const float*)d_in[6];
    const float* W3  = (const float*)d_in[7];
    const float* b3  = (const float*)d_in[8];
    const float* g2  = (const float*)d_in[9];
    const float* be2 = (const float*)d_in[10];
    const float* W4  = (const float*)d_in[11];
    const float* b4  = (const float*)d_in[12];
    float* ws  = (float*)d_ws;
    float* out = (float*)d_out;

    hipMemsetAsync(d_ws, 0, 4096, stream);   // control lines + BN2/moment accumulators
    void* args[] = {
        (void*)&xin, (void*)&W1, (void*)&b1, (void*)&g1, (void*)&be1,
        (void*)&W2, (void*)&b2, (void*)&W3, (void*)&b3, (void*)&g2,
        (void*)&be2, (void*)&W4, (void*)&b4, (void*)&ws, (void*)&out
    };
    hipLaunchCooperativeKernel((const void*)fused, dim3(256), dim3(512),
                               args, 0, stream);
}